// Round 10
// baseline (263.822 us; speedup 1.0000x reference)
//
#include <hip/hip_runtime.h>
#include <math.h>

#define LN_EPS 1e-5f

typedef short short8 __attribute__((ext_vector_type(8)));
typedef float f32x4  __attribute__((ext_vector_type(4)));
typedef float f32x2  __attribute__((ext_vector_type(2)));

// ---- bf16 helpers (bit-level; RNE on encode) ----
__device__ __forceinline__ unsigned short f2bf(float f) {
    unsigned u = __float_as_uint(f);
    u += 0x7FFFu + ((u >> 16) & 1u);
    return (unsigned short)(u >> 16);
}
__device__ __forceinline__ unsigned packbf2(float lo, float hi) {
    return (unsigned)f2bf(lo) | ((unsigned)f2bf(hi) << 16);
}
__device__ __forceinline__ float bflo(unsigned u) { return __uint_as_float(u << 16); }
__device__ __forceinline__ float bfhi(unsigned u) { return __uint_as_float(u & 0xFFFF0000u); }

// ---- fp8 e4m3 helpers (HW cvt; word selector must be a LITERAL constant) ----
__device__ __forceinline__ f32x2 fp8lo(unsigned u) {
    return __builtin_amdgcn_cvt_pk_f32_fp8((int)u, false);
}
__device__ __forceinline__ f32x2 fp8hi(unsigned u) {
    return __builtin_amdgcn_cvt_pk_f32_fp8((int)u, true);
}
__device__ __forceinline__ unsigned char f2fp8(float f) {
    return (unsigned char)(__builtin_amdgcn_cvt_pk_fp8_f32(f, f, 0, false) & 0xFF);
}

// ---------------------------------------------------------------------------
// Kernel 0: transpose weights to bf16 W^T  (WT[n][k] = W[k][n]).
// ---------------------------------------------------------------------------
__global__ __launch_bounds__(256) void prep_kernel(
    const float* __restrict__ W0, const float* __restrict__ W1,
    const float* __restrict__ W2, const float* __restrict__ W3,
    unsigned short* __restrict__ T0, unsigned short* __restrict__ T1,
    unsigned short* __restrict__ T2, unsigned short* __restrict__ T3)
{
    const float* W = (blockIdx.x == 0) ? W0 : (blockIdx.x == 1) ? W1
                   : (blockIdx.x == 2) ? W2 : W3;
    unsigned short* T = (blockIdx.x == 0) ? T0 : (blockIdx.x == 1) ? T1
                      : (blockIdx.x == 2) ? T2 : T3;
    const int t = threadIdx.x;
    const int n = (t & 31) * 4;
    for (int k = t >> 5; k < 128; k += 8) {
        float4 w = ((const float4*)W)[k * 32 + (t & 31)];
        T[(n + 0) * 128 + k] = f2bf(w.x);
        T[(n + 1) * 128 + k] = f2bf(w.y);
        T[(n + 2) * 128 + k] = f2bf(w.z);
        T[(n + 3) * 128 + k] = f2bf(w.w);
    }
}

// ---------------------------------------------------------------------------
// Kernel 1: Q/K/V GEMM via bf16 MFMA + fused dst histogram.
// Outputs fp8 e4m3: QV8 record per node = 16 chunks of 16B, chunk j =
// [Q dims 8j..8j+7 | V dims 8j..8j+7].  K8 = [node][128] fp8.
// ---------------------------------------------------------------------------
__global__ __launch_bounds__(256) void qkv_mfma(
    const float* __restrict__ x,
    const unsigned short* __restrict__ WqT, const unsigned short* __restrict__ WkT,
    const unsigned short* __restrict__ WvT,
    const float* __restrict__ bq, const float* __restrict__ bk,
    const float* __restrict__ bv,
    unsigned char* __restrict__ QV8, unsigned char* __restrict__ K8,
    const int* __restrict__ dst, int E, unsigned* __restrict__ cnt, int N)
{
    __shared__ unsigned short xs[128 * 128];   // 32 KB, swizzled
    const int tid  = threadIdx.x;
    const int base = blockIdx.x * 128;

    // fused dst histogram (independent of GEMM work)
    for (int e = blockIdx.x * 256 + tid; e < E; e += gridDim.x * 256)
        atomicAdd(&cnt[dst[e]], 1u);

    for (int g = tid; g < 2048; g += 256) {
        int row = g >> 4, c = g & 15;
        int node = base + row;
        float4 a, b;
        if (node < N) {
            a = ((const float4*)x)[(size_t)node * 32 + c * 2];
            b = ((const float4*)x)[(size_t)node * 32 + c * 2 + 1];
        } else {
            a = make_float4(0.f, 0.f, 0.f, 0.f);
            b = a;
        }
        uint4 pk;
        pk.x = packbf2(a.x, a.y);
        pk.y = packbf2(a.z, a.w);
        pk.z = packbf2(b.x, b.y);
        pk.w = packbf2(b.z, b.w);
        int sc = c ^ (row & 15);
        *(uint4*)&xs[row * 128 + sc * 8] = pk;
    }
    __syncthreads();

    const int lane = tid & 63;
    const int w    = tid >> 6;
    const int lr   = lane & 15;
    const int lg   = lane >> 4;

    short8 afrag[2][4];
#pragma unroll
    for (int mt = 0; mt < 2; ++mt)
#pragma unroll
        for (int ko = 0; ko < 4; ++ko) {
            int row = w * 32 + mt * 16 + lr;
            int sc  = (ko * 4 + lg) ^ lr;
            afrag[mt][ko] = *(const short8*)&xs[row * 128 + sc * 8];
        }

    const unsigned short* WTm[3] = {WqT, WkT, WvT};
    const float*          bm[3]  = {bq, bk, bv};

    for (int m = 0; m < 3; ++m) {
        const unsigned short* WT = WTm[m];
        f32x4 acc[2][8];
#pragma unroll
        for (int mt = 0; mt < 2; ++mt)
#pragma unroll
            for (int nt = 0; nt < 8; ++nt)
                acc[mt][nt] = (f32x4){0.f, 0.f, 0.f, 0.f};

#pragma unroll
        for (int nt = 0; nt < 8; ++nt) {
            short8 bfr[4];
#pragma unroll
            for (int ko = 0; ko < 4; ++ko) {
                int n = nt * 16 + lr;
                int k = ko * 32 + lg * 8;
                bfr[ko] = *(const short8*)&WT[n * 128 + k];
            }
#pragma unroll
            for (int mt = 0; mt < 2; ++mt)
#pragma unroll
                for (int ko = 0; ko < 4; ++ko)
                    acc[mt][nt] = __builtin_amdgcn_mfma_f32_16x16x32_bf16(
                        afrag[mt][ko], bfr[ko], acc[mt][nt], 0, 0, 0);
        }

        float bcol[8];
#pragma unroll
        for (int nt = 0; nt < 8; ++nt) bcol[nt] = bm[m][nt * 16 + lr];

#pragma unroll
        for (int mt = 0; mt < 2; ++mt)
#pragma unroll
            for (int i = 0; i < 4; ++i) {
                int node = base + w * 32 + mt * 16 + 4 * lg + i;
                if (node >= N) continue;
                if (m == 1) {
#pragma unroll
                    for (int nt = 0; nt < 8; ++nt)
                        K8[(size_t)node * 128 + nt * 16 + lr] =
                            f2fp8(acc[mt][nt][i] + bcol[nt]);
                } else {
                    // col c = nt*16+lr -> chunk j=c>>3, byte c&7; Q at +0, V at +8
                    const size_t rb = (size_t)node * 256 + (m == 0 ? 0 : 8)
                                    + (lr >> 3) * 16 + (lr & 7);
#pragma unroll
                    for (int nt = 0; nt < 8; ++nt)
                        QV8[rb + nt * 32] = f2fp8(acc[mt][nt][i] + bcol[nt]);
                }
            }
    }
}

// ---------------------------------------------------------------------------
// Kernel 3a: per-chunk exclusive scan (1024 elements/block) + block totals.
// ---------------------------------------------------------------------------
__global__ __launch_bounds__(1024) void scan1_kernel(
    const unsigned* __restrict__ cnt, unsigned* __restrict__ off,
    unsigned* __restrict__ bsum, int N)
{
    __shared__ unsigned sh[1024];
    const int t = threadIdx.x;
    const int gid = blockIdx.x * 1024 + t;
    unsigned v = (gid < N) ? cnt[gid] : 0u;
    sh[t] = v;
    __syncthreads();
#pragma unroll
    for (int d = 1; d < 1024; d <<= 1) {
        unsigned u = (t >= d) ? sh[t - d] : 0u;
        __syncthreads();
        sh[t] += u;
        __syncthreads();
    }
    if (gid < N) off[gid] = sh[t] - v;
    if (t == 1023) bsum[blockIdx.x] = sh[1023];
}

// ---------------------------------------------------------------------------
// Kernel 3b: scan block totals (single block); off[N] = total.
// ---------------------------------------------------------------------------
__global__ __launch_bounds__(1024) void scan2_kernel(
    const unsigned* __restrict__ bsum, unsigned* __restrict__ bbase,
    unsigned* __restrict__ off, int nb, int N)
{
    __shared__ unsigned sh[1024];
    const int t = threadIdx.x;
    unsigned v = (t < nb) ? bsum[t] : 0u;
    sh[t] = v;
    __syncthreads();
#pragma unroll
    for (int d = 1; d < 1024; d <<= 1) {
        unsigned u = (t >= d) ? sh[t - d] : 0u;
        __syncthreads();
        sh[t] += u;
        __syncthreads();
    }
    if (t < nb) bbase[t] = sh[t] - v;
    if (t == 1023) off[N] = sh[1023];
}

// ---------------------------------------------------------------------------
// Kernel 3c: add chunk base; write cursor copy.
// ---------------------------------------------------------------------------
__global__ __launch_bounds__(1024) void scan3_kernel(
    unsigned* __restrict__ off, unsigned* __restrict__ cursor,
    const unsigned* __restrict__ bbase, int N)
{
    const int gid = blockIdx.x * 1024 + threadIdx.x;
    if (gid < N) {
        unsigned o = off[gid] + bbase[blockIdx.x];
        off[gid] = o;
        cursor[gid] = o;
    }
}

// ---------------------------------------------------------------------------
// Kernel 4: reorder edge sources into CSR order (4B records).
// ---------------------------------------------------------------------------
__global__ __launch_bounds__(256) void reorder_kernel(
    const int* __restrict__ ei, int E,
    unsigned* __restrict__ cursor, int* __restrict__ rec_src)
{
    for (int e = blockIdx.x * blockDim.x + threadIdx.x; e < E;
         e += gridDim.x * blockDim.x) {
        int s = ei[e];
        int t = ei[E + e];
        unsigned pos = atomicAdd(&cursor[t], 1u);
        rec_src[pos] = s;
    }
}

// ---------------------------------------------------------------------------
// Kernel 5: fused per-node attention (fp8 gathers), PERSISTENT-WAVE version.
// Grid-stride over nodes: 2048 blocks x 4 waves = 8192 resident waves (100%
// of 256CU x 32 waves) processing ~6 nodes each -> no per-node workgroup
// launch/drain cost (12500 tiny WGs was the suspected throughput cap).
// Per node: 4 edge-slots x 16 lanes, unrolled x2; srcs prefetched
// (coalesced) and distributed via shfl.
// ---------------------------------------------------------------------------
__global__ __launch_bounds__(256) void node_attn_kernel(
    const unsigned char* __restrict__ QV8, const unsigned char* __restrict__ K8,
    const int* __restrict__ rec_src, const unsigned* __restrict__ off,
    unsigned short* __restrict__ aggb, float* __restrict__ partials, int N)
{
    const int lane = threadIdx.x & 63;
    const int wv   = threadIdx.x >> 6;
    const int g = lane >> 4;
    const int j = lane & 15;
    const float scale = 0.17677669529663687f;   // 1/sqrt(32)
    const int stride = gridDim.x * 4;

    for (int node = blockIdx.x * 4 + wv; node < N; node += stride) {
        const unsigned lo = off[node], hi = off[node + 1];

        // prefetch up to 64 edge sources (one coalesced load per wave)
        const unsigned safe = (hi > lo) ? lo : 0u;      // degree-0: stay in-bounds
        const int rs = rec_src[(lo + (unsigned)lane < hi) ? lo + lane : safe];

        // K[node] dims [8j, 8j+8) decoded to registers
        const uint2 kw = *(const uint2*)&K8[(size_t)node * 128 + j * 8];
        const f32x2 ka = fp8lo(kw.x), kb = fp8hi(kw.x);
        const f32x2 kc = fp8lo(kw.y), kd = fp8hi(kw.y);

        float acc[8] = {0.f, 0.f, 0.f, 0.f, 0.f, 0.f, 0.f, 0.f};
        float ls = 0.f;

        auto body8 = [&](int s0, int s1, bool val0, bool val1) {
            uint4 r0 = *(const uint4*)&QV8[(size_t)s0 * 256 + j * 16];
            uint4 r1 = *(const uint4*)&QV8[(size_t)s1 * 256 + j * 16];

            f32x2 qa0 = fp8lo(r0.x), qb0 = fp8hi(r0.x);
            f32x2 qc0 = fp8lo(r0.y), qd0 = fp8hi(r0.y);
            f32x2 qa1 = fp8lo(r1.x), qb1 = fp8hi(r1.x);
            f32x2 qc1 = fp8lo(r1.y), qd1 = fp8hi(r1.y);

            float p0 = qa0.x * ka.x + qa0.y * ka.y + qb0.x * kb.x + qb0.y * kb.y
                     + qc0.x * kc.x + qc0.y * kc.y + qd0.x * kd.x + qd0.y * kd.y;
            float p1 = qa1.x * ka.x + qa1.y * ka.y + qb1.x * kb.x + qb1.y * kb.y
                     + qc1.x * kc.x + qc1.y * kc.y + qd1.x * kd.x + qd1.y * kd.y;

            p0 += __shfl_xor(p0, 1);
            p1 += __shfl_xor(p1, 1);
            p0 += __shfl_xor(p0, 2);
            p1 += __shfl_xor(p1, 2);   // full 32-dim head dot per 4-lane group

            float sv0 = p0 * scale;
            sv0 = (sv0 >= 0.f) ? sv0 : 0.2f * sv0;     // LeakyReLU(0.2)
            float a0 = val0 ? __expf(sv0) : 0.f;       // global softmax: no shift
            float sv1 = p1 * scale;
            sv1 = (sv1 >= 0.f) ? sv1 : 0.2f * sv1;
            float a1 = val1 ? __expf(sv1) : 0.f;
            if ((j & 3) == 0) ls += a0 + a1;

            f32x2 va0 = fp8lo(r0.z), vb0 = fp8hi(r0.z);
            f32x2 vc0 = fp8lo(r0.w), vd0 = fp8hi(r0.w);
            f32x2 va1 = fp8lo(r1.z), vb1 = fp8hi(r1.z);
            f32x2 vc1 = fp8lo(r1.w), vd1 = fp8hi(r1.w);

            acc[0] = fmaf(a0, va0.x, acc[0]);
            acc[1] = fmaf(a0, va0.y, acc[1]);
            acc[2] = fmaf(a0, vb0.x, acc[2]);
            acc[3] = fmaf(a0, vb0.y, acc[3]);
            acc[4] = fmaf(a0, vc0.x, acc[4]);
            acc[5] = fmaf(a0, vc0.y, acc[5]);
            acc[6] = fmaf(a0, vd0.x, acc[6]);
            acc[7] = fmaf(a0, vd0.y, acc[7]);

            acc[0] = fmaf(a1, va1.x, acc[0]);
            acc[1] = fmaf(a1, va1.y, acc[1]);
            acc[2] = fmaf(a1, vb1.x, acc[2]);
            acc[3] = fmaf(a1, vb1.y, acc[3]);
            acc[4] = fmaf(a1, vc1.x, acc[4]);
            acc[5] = fmaf(a1, vc1.y, acc[5]);
            acc[6] = fmaf(a1, vd1.x, acc[6]);
            acc[7] = fmaf(a1, vd1.y, acc[7]);
        };

        const unsigned hi64 = (hi - lo > 64u) ? lo + 64u : hi;

        for (unsigned i = lo; i < hi64; i += 8) {
            unsigned e0 = i + g, e1 = i + 4 + g;
            int s0 = __shfl(rs, (int)((e0 - lo) & 63u));
            int s1 = __shfl(rs, (int)((e1 - lo) & 63u));
            body8(s0, s1, e0 < hi64, e1 < hi64);
        }
        // rare tail: degree > 64 (direct loads)
        for (unsigned i = hi64; i < hi; i += 8) {
            unsigned e0 = i + g, e1 = i + 4 + g;
            bool val0 = e0 < hi, val1 = e1 < hi;
            int s0 = rec_src[val0 ? e0 : lo];
            int s1 = rec_src[val1 ? e1 : lo];
            body8(s0, s1, val0, val1);
        }

#pragma unroll
        for (int k = 0; k < 8; ++k) {
            acc[k] += __shfl_xor(acc[k], 16);
            acc[k] += __shfl_xor(acc[k], 32);
        }
        ls += __shfl_xor(ls, 16);
        ls += __shfl_xor(ls, 32);

        if (lane < 16) {
            uint4 o;
            o.x = packbf2(acc[0], acc[1]);
            o.y = packbf2(acc[2], acc[3]);
            o.z = packbf2(acc[4], acc[5]);
            o.w = packbf2(acc[6], acc[7]);
            *(uint4*)&aggb[(size_t)node * 128 + j * 8] = o;
            if ((j & 3) == 0)
                atomicAdd(&partials[(node & 63) * 4 + (j >> 2)], ls);
        }
    }
}

// ---------------------------------------------------------------------------
// Kernel 6: h = (aggb * inv_sum) @ Wo + bo via MFMA; y = x + h; LayerNorm.
// ---------------------------------------------------------------------------
__global__ __launch_bounds__(256) void out_mfma(
    const float* __restrict__ x, const unsigned short* __restrict__ aggb,
    const unsigned short* __restrict__ WoT,
    const float* __restrict__ bo, const float* __restrict__ gamma,
    const float* __restrict__ beta, const float* __restrict__ partials,
    float* __restrict__ out, int N)
{
    __shared__ unsigned short as_[128 * 128];   // 32 KB, swizzled
    __shared__ float invs[4];
    const int tid  = threadIdx.x;
    const int base = blockIdx.x * 128;

    if (tid < 64) {
        float4 ps = ((const float4*)partials)[tid];
#pragma unroll
        for (int m = 1; m < 64; m <<= 1) {
            ps.x += __shfl_xor(ps.x, m);
            ps.y += __shfl_xor(ps.y, m);
            ps.z += __shfl_xor(ps.z, m);
            ps.w += __shfl_xor(ps.w, m);
        }
        if (tid == 0) {
            invs[0] = 1.f / ps.x; invs[1] = 1.f / ps.y;
            invs[2] = 1.f / ps.z; invs[3] = 1.f / ps.w;
        }
    }
    __syncthreads();

    for (int g = tid; g < 2048; g += 256) {
        int row = g >> 4, c = g & 15;
        int node = base + row;
        uint4 v = (node < N) ? *(const uint4*)&aggb[(size_t)node * 128 + c * 8]
                             : make_uint4(0u, 0u, 0u, 0u);
        float iv = invs[c >> 2];   // chunk c covers dims [8c,8c+8) -> head c>>2
        uint4 pk;
        pk.x = packbf2(bflo(v.x) * iv, bfhi(v.x) * iv);
        pk.y = packbf2(bflo(v.y) * iv, bfhi(v.y) * iv);
        pk.z = packbf2(bflo(v.z) * iv, bfhi(v.z) * iv);
        pk.w = packbf2(bflo(v.w) * iv, bfhi(v.w) * iv);
        int sc = c ^ (row & 15);
        *(uint4*)&as_[row * 128 + sc * 8] = pk;
    }
    __syncthreads();

    const int lane = tid & 63;
    const int w    = tid >> 6;
    const int lr   = lane & 15;
    const int lg   = lane >> 4;

    short8 afrag[2][4];
#pragma unroll
    for (int mt = 0; mt < 2; ++mt)
#pragma unroll
        for (int ko = 0; ko < 4; ++ko) {
            int row = w * 32 + mt * 16 + lr;
            int sc  = (ko * 4 + lg) ^ lr;
            afrag[mt][ko] = *(const short8*)&as_[row * 128 + sc * 8];
        }

    f32x4 acc[2][8];
#pragma unroll
    for (int mt = 0; mt < 2; ++mt)
#pragma unroll
        for (int nt = 0; nt < 8; ++nt)
            acc[mt][nt] = (f32x4){0.f, 0.f, 0.f, 0.f};

#pragma unroll
    for (int nt = 0; nt < 8; ++nt) {
        short8 bfr[4];
#pragma unroll
        for (int ko = 0; ko < 4; ++ko) {
            int n = nt * 16 + lr;
            int k = ko * 32 + lg * 8;
            bfr[ko] = *(const short8*)&WoT[n * 128 + k];
        }
#pragma unroll
        for (int mt = 0; mt < 2; ++mt)
#pragma unroll
            for (int ko = 0; ko < 4; ++ko)
                acc[mt][nt] = __builtin_amdgcn_mfma_f32_16x16x32_bf16(
                    afrag[mt][ko], bfr[ko], acc[mt][nt], 0, 0, 0);
    }

    float bo8[8], gg8[8], bb8[8];
#pragma unroll
    for (int nt = 0; nt < 8; ++nt) {
        bo8[nt] = bo[nt * 16 + lr];
        gg8[nt] = gamma[nt * 16 + lr];
        bb8[nt] = beta[nt * 16 + lr];
    }

#pragma unroll
    for (int mt = 0; mt < 2; ++mt)
#pragma unroll
        for (int i = 0; i < 4; ++i) {
            int node = base + w * 32 + mt * 16 + 4 * lg + i;
            if (node >= N) continue;
            float y8[8];
            float ps = 0.f;
#pragma unroll
            for (int nt = 0; nt < 8; ++nt) {
                float y = acc[mt][nt][i] + bo8[nt]
                        + x[(size_t)node * 128 + nt * 16 + lr];
                y8[nt] = y;
                ps += y;
            }
#pragma unroll
            for (int m = 1; m < 16; m <<= 1) ps += __shfl_xor(ps, m);
            float mu = ps * (1.0f / 128.0f);

            float pv = 0.f;
#pragma unroll
            for (int nt = 0; nt < 8; ++nt) {
                float d = y8[nt] - mu;
                pv = fmaf(d, d, pv);
            }
#pragma unroll
            for (int m = 1; m < 16; m <<= 1) pv += __shfl_xor(pv, m);
            float rstd = rsqrtf(pv * (1.0f / 128.0f) + LN_EPS);

#pragma unroll
            for (int nt = 0; nt < 8; ++nt)
                out[(size_t)node * 128 + nt * 16 + lr] =
                    (y8[nt] - mu) * rstd * gg8[nt] + bb8[nt];
        }
}

// ---------------------------------------------------------------------------
extern "C" void kernel_launch(void* const* d_in, const int* in_sizes, int n_in,
                              void* d_out, int out_size, void* d_ws, size_t ws_size,
                              hipStream_t stream)
{
    const float* x     = (const float*)d_in[0];
    const int*   ei    = (const int*)d_in[1];
    const float* Wq    = (const float*)d_in[2];
    const float* bq    = (const float*)d_in[3];
    const float* Wk    = (const float*)d_in[4];
    const float* bk    = (const float*)d_in[5];
    const float* Wv    = (const float*)d_in[6];
    const float* bv    = (const float*)d_in[7];
    const float* Wo    = (const float*)d_in[8];
    const float* bo    = (const float*)d_in[9];
    const float* gamma = (const float*)d_in[10];
    const float* beta  = (const float*)d_in[11];
    float* out = (float*)d_out;

    const int N = in_sizes[0] / 128;
    const int E = in_sizes[1] / 2;

    // workspace layout
    char* p = (char*)d_ws;
    unsigned char*  QV8  = (unsigned char*)p;  p += (size_t)N * 256;   // fp8 Q||V
    unsigned char*  K8   = (unsigned char*)p;  p += (size_t)N * 128;   // fp8 K
    unsigned short* aggb = (unsigned short*)p; p += (size_t)N * 128 * 2;
    int* rec_src = (int*)p; p += (size_t)E * 4;
    unsigned short* WqT = (unsigned short*)p; p += 16384 * 2;
    unsigned short* WkT = (unsigned short*)p; p += 16384 * 2;
    unsigned short* WvT = (unsigned short*)p; p += 16384 * 2;
    unsigned short* WoT = (unsigned short*)p; p += 16384 * 2;
    float*    partials = (float*)p;  p += 256 * 4;          // 64 buckets x 4 heads
    unsigned* cnt      = (unsigned*)p; p += (size_t)N * 4;
    unsigned* off      = (unsigned*)p; p += (size_t)(N + 1) * 4;
    unsigned* cursor   = (unsigned*)p; p += (size_t)N * 4;
    unsigned* bsum     = (unsigned*)p; p += 1024 * 4;
    unsigned* bbase    = (unsigned*)p;

    // zero partials + cnt (contiguous)
    (void)hipMemsetAsync(partials, 0, (size_t)(256 + N) * sizeof(unsigned), stream);

    const int nb  = (N + 127) / 128;
    const int nsc = (N + 1023) / 1024;
    prep_kernel<<<4, 256, 0, stream>>>(Wq, Wk, Wv, Wo, WqT, WkT, WvT, WoT);
    qkv_mfma<<<nb, 256, 0, stream>>>(x, WqT, WkT, WvT, bq, bk, bv,
                                     QV8, K8, ei + E, E, cnt, N);
    scan1_kernel<<<nsc, 1024, 0, stream>>>(cnt, off, bsum, N);
    scan2_kernel<<<1, 1024, 0, stream>>>(bsum, bbase, off, nsc, N);
    scan3_kernel<<<nsc, 1024, 0, stream>>>(off, cursor, bbase, N);
    reorder_kernel<<<1024, 256, 0, stream>>>(ei, E, cursor, rec_src);
    node_attn_kernel<<<2048, 256, 0, stream>>>(QV8, K8, rec_src, off,
                                               aggb, partials, N);
    out_mfma<<<nb, 256, 0, stream>>>(x, aggb, WoT, bo, gamma, beta, partials,
                                     out, N);
}

// Round 11
// 254.388 us; speedup vs baseline: 1.0371x; 1.0371x over previous
//
#include <hip/hip_runtime.h>
#include <math.h>

#define LN_EPS 1e-5f
#define CHUNK_SHIFT 14   // src chunks of 16384 nodes (~4MB QV8 slice, fits XCD L2)
#define NCHUNK 4

typedef short short8 __attribute__((ext_vector_type(8)));
typedef float f32x4  __attribute__((ext_vector_type(4)));
typedef float f32x2  __attribute__((ext_vector_type(2)));

// ---- bf16 helpers ----
__device__ __forceinline__ unsigned short f2bf(float f) {
    unsigned u = __float_as_uint(f);
    u += 0x7FFFu + ((u >> 16) & 1u);
    return (unsigned short)(u >> 16);
}
__device__ __forceinline__ unsigned packbf2(float lo, float hi) {
    return (unsigned)f2bf(lo) | ((unsigned)f2bf(hi) << 16);
}
__device__ __forceinline__ float bflo(unsigned u) { return __uint_as_float(u << 16); }
__device__ __forceinline__ float bfhi(unsigned u) { return __uint_as_float(u & 0xFFFF0000u); }

// ---- fp8 e4m3 helpers (HW cvt; word selector must be literal) ----
__device__ __forceinline__ f32x2 fp8lo(unsigned u) {
    return __builtin_amdgcn_cvt_pk_f32_fp8((int)u, false);
}
__device__ __forceinline__ f32x2 fp8hi(unsigned u) {
    return __builtin_amdgcn_cvt_pk_f32_fp8((int)u, true);
}
__device__ __forceinline__ unsigned char f2fp8(float f) {
    return (unsigned char)(__builtin_amdgcn_cvt_pk_fp8_f32(f, f, 0, false) & 0xFF);
}

// ---------------------------------------------------------------------------
// Kernel 0: transpose weights to bf16 W^T  (WT[n][k] = W[k][n]).
// ---------------------------------------------------------------------------
__global__ __launch_bounds__(256) void prep_kernel(
    const float* __restrict__ W0, const float* __restrict__ W1,
    const float* __restrict__ W2, const float* __restrict__ W3,
    unsigned short* __restrict__ T0, unsigned short* __restrict__ T1,
    unsigned short* __restrict__ T2, unsigned short* __restrict__ T3)
{
    const float* W = (blockIdx.x == 0) ? W0 : (blockIdx.x == 1) ? W1
                   : (blockIdx.x == 2) ? W2 : W3;
    unsigned short* T = (blockIdx.x == 0) ? T0 : (blockIdx.x == 1) ? T1
                      : (blockIdx.x == 2) ? T2 : T3;
    const int t = threadIdx.x;
    const int n = (t & 31) * 4;
    for (int k = t >> 5; k < 128; k += 8) {
        float4 w = ((const float4*)W)[k * 32 + (t & 31)];
        T[(n + 0) * 128 + k] = f2bf(w.x);
        T[(n + 1) * 128 + k] = f2bf(w.y);
        T[(n + 2) * 128 + k] = f2bf(w.z);
        T[(n + 3) * 128 + k] = f2bf(w.w);
    }
}

// ---------------------------------------------------------------------------
// Kernel 1: Q/K/V GEMM via bf16 MFMA + fused (dst,src-chunk) histogram.
// fp8 outputs staged in LDS then stored with coalesced uint4 writes
// (replaces 192 divergent byte-stores/thread).
// QV8 record per node = 16 chunks of 16B: [Q dims 8j..8j+7 | V dims 8j..8j+7].
// ---------------------------------------------------------------------------
__global__ __launch_bounds__(256) void qkv_mfma(
    const float* __restrict__ x,
    const unsigned short* __restrict__ WqT, const unsigned short* __restrict__ WkT,
    const unsigned short* __restrict__ WvT,
    const float* __restrict__ bq, const float* __restrict__ bk,
    const float* __restrict__ bv,
    unsigned char* __restrict__ QV8, unsigned char* __restrict__ K8,
    const int* __restrict__ ei, int E, unsigned* __restrict__ cnt, int N)
{
    __shared__ unsigned char sm[32768 + 16384];   // 48 KB
    unsigned short* xs  = (unsigned short*)sm;    // x tile (32KB), dead after afrag
    unsigned char*  qvs = sm;                     // fp8 QV staging (aliases xs)
    unsigned char*  ks  = sm + 32768;             // fp8 K staging (16KB)

    const int tid  = threadIdx.x;
    const int base = blockIdx.x * 128;

    // fused (dst, src-chunk) histogram
    for (int e = blockIdx.x * 256 + tid; e < E; e += gridDim.x * 256) {
        int s = ei[e];
        int t = ei[E + e];
        atomicAdd(&cnt[t * NCHUNK + (s >> CHUNK_SHIFT)], 1u);
    }

    for (int g = tid; g < 2048; g += 256) {
        int row = g >> 4, c = g & 15;
        int node = base + row;
        float4 a, b;
        if (node < N) {
            a = ((const float4*)x)[(size_t)node * 32 + c * 2];
            b = ((const float4*)x)[(size_t)node * 32 + c * 2 + 1];
        } else {
            a = make_float4(0.f, 0.f, 0.f, 0.f);
            b = a;
        }
        uint4 pk;
        pk.x = packbf2(a.x, a.y);
        pk.y = packbf2(a.z, a.w);
        pk.z = packbf2(b.x, b.y);
        pk.w = packbf2(b.z, b.w);
        int sc = c ^ (row & 15);
        *(uint4*)&xs[row * 128 + sc * 8] = pk;
    }
    __syncthreads();

    const int lane = tid & 63;
    const int w    = tid >> 6;
    const int lr   = lane & 15;
    const int lg   = lane >> 4;

    short8 afrag[2][4];
#pragma unroll
    for (int mt = 0; mt < 2; ++mt)
#pragma unroll
        for (int ko = 0; ko < 4; ++ko) {
            int row = w * 32 + mt * 16 + lr;
            int sc  = (ko * 4 + lg) ^ lr;
            afrag[mt][ko] = *(const short8*)&xs[row * 128 + sc * 8];
        }
    __syncthreads();   // xs is now dead; sm may be reused for fp8 staging

    const unsigned short* WTm[3] = {WqT, WkT, WvT};
    const float*          bm[3]  = {bq, bk, bv};

    for (int m = 0; m < 3; ++m) {
        const unsigned short* WT = WTm[m];
        f32x4 acc[2][8];
#pragma unroll
        for (int mt = 0; mt < 2; ++mt)
#pragma unroll
            for (int nt = 0; nt < 8; ++nt)
                acc[mt][nt] = (f32x4){0.f, 0.f, 0.f, 0.f};

#pragma unroll
        for (int nt = 0; nt < 8; ++nt) {
            short8 bfr[4];
#pragma unroll
            for (int ko = 0; ko < 4; ++ko) {
                int n = nt * 16 + lr;
                int k = ko * 32 + lg * 8;
                bfr[ko] = *(const short8*)&WT[n * 128 + k];
            }
#pragma unroll
            for (int mt = 0; mt < 2; ++mt)
#pragma unroll
                for (int ko = 0; ko < 4; ++ko)
                    acc[mt][nt] = __builtin_amdgcn_mfma_f32_16x16x32_bf16(
                        afrag[mt][ko], bfr[ko], acc[mt][nt], 0, 0, 0);
        }

        float bcol[8];
#pragma unroll
        for (int nt = 0; nt < 8; ++nt) bcol[nt] = bm[m][nt * 16 + lr];

        // stage fp8 into LDS (block-local rows 0..127)
#pragma unroll
        for (int mt = 0; mt < 2; ++mt)
#pragma unroll
            for (int i = 0; i < 4; ++i) {
                int row = w * 32 + mt * 16 + 4 * lg + i;
                if (m == 1) {
#pragma unroll
                    for (int nt = 0; nt < 8; ++nt)
                        ks[row * 128 + nt * 16 + lr] =
                            f2fp8(acc[mt][nt][i] + bcol[nt]);
                } else {
                    int rb = row * 256 + (m == 0 ? 0 : 8)
                           + (lr >> 3) * 16 + (lr & 7);
#pragma unroll
                    for (int nt = 0; nt < 8; ++nt)
                        qvs[rb + nt * 32] = f2fp8(acc[mt][nt][i] + bcol[nt]);
                }
            }
    }
    __syncthreads();

    // cooperative coalesced stores
    for (int i = tid; i < 2048; i += 256) {          // QV: 128 rows x 16 uint4
        int row = i >> 4;
        if (base + row < N)
            *(uint4*)&QV8[(size_t)(base + row) * 256 + (i & 15) * 16] =
                *(const uint4*)&qvs[i * 16];
    }
    for (int i = tid; i < 1024; i += 256) {          // K: 128 rows x 8 uint4
        int row = i >> 3;
        if (base + row < N)
            *(uint4*)&K8[(size_t)(base + row) * 128 + (i & 7) * 16] =
                *(const uint4*)&ks[i * 16];
    }
}

// ---------------------------------------------------------------------------
// Kernel 3a/3b/3c: hierarchical exclusive scan over 4N buckets.
// ---------------------------------------------------------------------------
__global__ __launch_bounds__(1024) void scan1_kernel(
    const unsigned* __restrict__ cnt, unsigned* __restrict__ off,
    unsigned* __restrict__ bsum, int NB)
{
    __shared__ unsigned sh[1024];
    const int t = threadIdx.x;
    const int gid = blockIdx.x * 1024 + t;
    unsigned v = (gid < NB) ? cnt[gid] : 0u;
    sh[t] = v;
    __syncthreads();
#pragma unroll
    for (int d = 1; d < 1024; d <<= 1) {
        unsigned u = (t >= d) ? sh[t - d] : 0u;
        __syncthreads();
        sh[t] += u;
        __syncthreads();
    }
    if (gid < NB) off[gid] = sh[t] - v;
    if (t == 1023) bsum[blockIdx.x] = sh[1023];
}

__global__ __launch_bounds__(1024) void scan2_kernel(
    const unsigned* __restrict__ bsum, unsigned* __restrict__ bbase,
    unsigned* __restrict__ off, int nb, int NB)
{
    __shared__ unsigned sh[1024];
    const int t = threadIdx.x;
    unsigned v = (t < nb) ? bsum[t] : 0u;
    sh[t] = v;
    __syncthreads();
#pragma unroll
    for (int d = 1; d < 1024; d <<= 1) {
        unsigned u = (t >= d) ? sh[t - d] : 0u;
        __syncthreads();
        sh[t] += u;
        __syncthreads();
    }
    if (t < nb) bbase[t] = sh[t] - v;
    if (t == 1023) off[NB] = sh[1023];
}

__global__ __launch_bounds__(1024) void scan3_kernel(
    unsigned* __restrict__ off, unsigned* __restrict__ cursor,
    const unsigned* __restrict__ bbase, int NB)
{
    const int gid = blockIdx.x * 1024 + threadIdx.x;
    if (gid < NB) {
        unsigned o = off[gid] + bbase[blockIdx.x];
        off[gid] = o;
        cursor[gid] = o;
    }
}

// ---------------------------------------------------------------------------
// Kernel 4: reorder edge sources into (dst, src-chunk)-bucketed CSR order.
// ---------------------------------------------------------------------------
__global__ __launch_bounds__(256) void reorder_kernel(
    const int* __restrict__ ei, int E,
    unsigned* __restrict__ cursor, int* __restrict__ rec_src)
{
    for (int e = blockIdx.x * blockDim.x + threadIdx.x; e < E;
         e += gridDim.x * blockDim.x) {
        int s = ei[e];
        int t = ei[E + e];
        unsigned pos = atomicAdd(&cursor[t * NCHUNK + (s >> CHUNK_SHIFT)], 1u);
        rec_src[pos] = s;
    }
}

// ---------------------------------------------------------------------------
// Kernel 5: fused per-node attention (fp8 gathers).  One wave per dst node;
// 4 edge-slots x 16 lanes, unrolled x2.  Edge lists are src-chunk-ordered:
// concurrently-resident waves sweep chunk 0->3 together, so gathers mostly
// hit an L2-resident ~3.2MB QV8 slice (the MSHR/latency fix).
// ---------------------------------------------------------------------------
__global__ __launch_bounds__(256) void node_attn_kernel(
    const unsigned char* __restrict__ QV8, const unsigned char* __restrict__ K8,
    const int* __restrict__ rec_src, const unsigned* __restrict__ off,
    unsigned short* __restrict__ aggb, float* __restrict__ partials, int N)
{
    const int node = blockIdx.x * 4 + (threadIdx.x >> 6);
    if (node >= N) return;
    const int lane = threadIdx.x & 63;
    const int g = lane >> 4;
    const int j = lane & 15;
    const float scale = 0.17677669529663687f;   // 1/sqrt(32)

    const unsigned lo = off[node * NCHUNK];
    const unsigned hi = off[node * NCHUNK + NCHUNK];

    const uint2 kw = *(const uint2*)&K8[(size_t)node * 128 + j * 8];
    const f32x2 ka = fp8lo(kw.x), kb = fp8hi(kw.x);
    const f32x2 kc = fp8lo(kw.y), kd = fp8hi(kw.y);

    float acc[8] = {0.f, 0.f, 0.f, 0.f, 0.f, 0.f, 0.f, 0.f};
    float ls = 0.f;

    for (unsigned i = lo; i < hi; i += 8) {
        unsigned e0 = i + g, e1 = i + 4 + g;
        bool val0 = e0 < hi, val1 = e1 < hi;
        int s0 = rec_src[val0 ? e0 : lo];
        int s1 = rec_src[val1 ? e1 : lo];
        uint4 r0 = *(const uint4*)&QV8[(size_t)s0 * 256 + j * 16];
        uint4 r1 = *(const uint4*)&QV8[(size_t)s1 * 256 + j * 16];

        f32x2 qa0 = fp8lo(r0.x), qb0 = fp8hi(r0.x);
        f32x2 qc0 = fp8lo(r0.y), qd0 = fp8hi(r0.y);
        f32x2 qa1 = fp8lo(r1.x), qb1 = fp8hi(r1.x);
        f32x2 qc1 = fp8lo(r1.y), qd1 = fp8hi(r1.y);

        float p0 = qa0.x * ka.x + qa0.y * ka.y + qb0.x * kb.x + qb0.y * kb.y
                 + qc0.x * kc.x + qc0.y * kc.y + qd0.x * kd.x + qd0.y * kd.y;
        float p1 = qa1.x * ka.x + qa1.y * ka.y + qb1.x * kb.x + qb1.y * kb.y
                 + qc1.x * kc.x + qc1.y * kc.y + qd1.x * kd.x + qd1.y * kd.y;

        p0 += __shfl_xor(p0, 1);
        p1 += __shfl_xor(p1, 1);
        p0 += __shfl_xor(p0, 2);
        p1 += __shfl_xor(p1, 2);   // full 32-dim head dot per 4-lane group

        float sv0 = p0 * scale;
        sv0 = (sv0 >= 0.f) ? sv0 : 0.2f * sv0;     // LeakyReLU(0.2)
        float a0 = val0 ? __expf(sv0) : 0.f;       // global softmax: no max shift
        float sv1 = p1 * scale;
        sv1 = (sv1 >= 0.f) ? sv1 : 0.2f * sv1;
        float a1 = val1 ? __expf(sv1) : 0.f;
        if ((j & 3) == 0) ls += a0 + a1;

        f32x2 va0 = fp8lo(r0.z), vb0 = fp8hi(r0.z);
        f32x2 vc0 = fp8lo(r0.w), vd0 = fp8hi(r0.w);
        f32x2 va1 = fp8lo(r1.z), vb1 = fp8hi(r1.z);
        f32x2 vc1 = fp8lo(r1.w), vd1 = fp8hi(r1.w);

        acc[0] = fmaf(a0, va0.x, acc[0]);
        acc[1] = fmaf(a0, va0.y, acc[1]);
        acc[2] = fmaf(a0, vb0.x, acc[2]);
        acc[3] = fmaf(a0, vb0.y, acc[3]);
        acc[4] = fmaf(a0, vc0.x, acc[4]);
        acc[5] = fmaf(a0, vc0.y, acc[5]);
        acc[6] = fmaf(a0, vd0.x, acc[6]);
        acc[7] = fmaf(a0, vd0.y, acc[7]);

        acc[0] = fmaf(a1, va1.x, acc[0]);
        acc[1] = fmaf(a1, va1.y, acc[1]);
        acc[2] = fmaf(a1, vb1.x, acc[2]);
        acc[3] = fmaf(a1, vb1.y, acc[3]);
        acc[4] = fmaf(a1, vc1.x, acc[4]);
        acc[5] = fmaf(a1, vc1.y, acc[5]);
        acc[6] = fmaf(a1, vd1.x, acc[6]);
        acc[7] = fmaf(a1, vd1.y, acc[7]);
    }

#pragma unroll
    for (int k = 0; k < 8; ++k) {
        acc[k] += __shfl_xor(acc[k], 16);
        acc[k] += __shfl_xor(acc[k], 32);
    }
    ls += __shfl_xor(ls, 16);
    ls += __shfl_xor(ls, 32);

    if (lane < 16) {
        uint4 o;
        o.x = packbf2(acc[0], acc[1]);
        o.y = packbf2(acc[2], acc[3]);
        o.z = packbf2(acc[4], acc[5]);
        o.w = packbf2(acc[6], acc[7]);
        *(uint4*)&aggb[(size_t)node * 128 + j * 8] = o;
        if ((j & 3) == 0)
            atomicAdd(&partials[(blockIdx.x & 63) * 4 + (j >> 2)], ls);
    }
}

// ---------------------------------------------------------------------------
// Kernel 6: h = (aggb * inv_sum) @ Wo + bo via MFMA; y = x + h; LayerNorm.
// ---------------------------------------------------------------------------
__global__ __launch_bounds__(256) void out_mfma(
    const float* __restrict__ x, const unsigned short* __restrict__ aggb,
    const unsigned short* __restrict__ WoT,
    const float* __restrict__ bo, const float* __restrict__ gamma,
    const float* __restrict__ beta, const float* __restrict__ partials,
    float* __restrict__ out, int N)
{
    __shared__ unsigned short as_[128 * 128];   // 32 KB, swizzled
    __shared__ float invs[4];
    const int tid  = threadIdx.x;
    const int base = blockIdx.x * 128;

    if (tid < 64) {
        float4 ps = ((const float4*)partials)[tid];
#pragma unroll
        for (int m = 1; m < 64; m <<= 1) {
            ps.x += __shfl_xor(ps.x, m);
            ps.y += __shfl_xor(ps.y, m);
            ps.z += __shfl_xor(ps.z, m);
            ps.w += __shfl_xor(ps.w, m);
        }
        if (tid == 0) {
            invs[0] = 1.f / ps.x; invs[1] = 1.f / ps.y;
            invs[2] = 1.f / ps.z; invs[3] = 1.f / ps.w;
        }
    }
    __syncthreads();

    for (int g = tid; g < 2048; g += 256) {
        int row = g >> 4, c = g & 15;
        int node = base + row;
        uint4 v = (node < N) ? *(const uint4*)&aggb[(size_t)node * 128 + c * 8]
                             : make_uint4(0u, 0u, 0u, 0u);
        float iv = invs[c >> 2];
        uint4 pk;
        pk.x = packbf2(bflo(v.x) * iv, bfhi(v.x) * iv);
        pk.y = packbf2(bflo(v.y) * iv, bfhi(v.y) * iv);
        pk.z = packbf2(bflo(v.z) * iv, bfhi(v.z) * iv);
        pk.w = packbf2(bflo(v.w) * iv, bfhi(v.w) * iv);
        int sc = c ^ (row & 15);
        *(uint4*)&as_[row * 128 + sc * 8] = pk;
    }
    __syncthreads();

    const int lane = tid & 63;
    const int w    = tid >> 6;
    const int lr   = lane & 15;
    const int lg   = lane >> 4;

    short8 afrag[2][4];
#pragma unroll
    for (int mt = 0; mt < 2; ++mt)
#pragma unroll
        for (int ko = 0; ko < 4; ++ko) {
            int row = w * 32 + mt * 16 + lr;
            int sc  = (ko * 4 + lg) ^ lr;
            afrag[mt][ko] = *(const short8*)&as_[row * 128 + sc * 8];
        }

    f32x4 acc[2][8];
#pragma unroll
    for (int mt = 0; mt < 2; ++mt)
#pragma unroll
        for (int nt = 0; nt < 8; ++nt)
            acc[mt][nt] = (f32x4){0.f, 0.f, 0.f, 0.f};

#pragma unroll
    for (int nt = 0; nt < 8; ++nt) {
        short8 bfr[4];
#pragma unroll
        for (int ko = 0; ko < 4; ++ko) {
            int n = nt * 16 + lr;
            int k = ko * 32 + lg * 8;
            bfr[ko] = *(const short8*)&WoT[n * 128 + k];
        }
#pragma unroll
        for (int mt = 0; mt < 2; ++mt)
#pragma unroll
            for (int ko = 0; ko < 4; ++ko)
                acc[mt][nt] = __builtin_amdgcn_mfma_f32_16x16x32_bf16(
                    afrag[mt][ko], bfr[ko], acc[mt][nt], 0, 0, 0);
    }

    float bo8[8], gg8[8], bb8[8];
#pragma unroll
    for (int nt = 0; nt < 8; ++nt) {
        bo8[nt] = bo[nt * 16 + lr];
        gg8[nt] = gamma[nt * 16 + lr];
        bb8[nt] = beta[nt * 16 + lr];
    }

#pragma unroll
    for (int mt = 0; mt < 2; ++mt)
#pragma unroll
        for (int i = 0; i < 4; ++i) {
            int node = base + w * 32 + mt * 16 + 4 * lg + i;
            if (node >= N) continue;
            float y8[8];
            float ps = 0.f;
#pragma unroll
            for (int nt = 0; nt < 8; ++nt) {
                float y = acc[mt][nt][i] + bo8[nt]
                        + x[(size_t)node * 128 + nt * 16 + lr];
                y8[nt] = y;
                ps += y;
            }
#pragma unroll
            for (int m = 1; m < 16; m <<= 1) ps += __shfl_xor(ps, m);
            float mu = ps * (1.0f / 128.0f);

            float pv = 0.f;
#pragma unroll
            for (int nt = 0; nt < 8; ++nt) {
                float d = y8[nt] - mu;
                pv = fmaf(d, d, pv);
            }
#pragma unroll
            for (int m = 1; m < 16; m <<= 1) pv += __shfl_xor(pv, m);
            float rstd = rsqrtf(pv * (1.0f / 128.0f) + LN_EPS);

#pragma unroll
            for (int nt = 0; nt < 8; ++nt)
                out[(size_t)node * 128 + nt * 16 + lr] =
                    (y8[nt] - mu) * rstd * gg8[nt] + bb8[nt];
        }
}

// ---------------------------------------------------------------------------
extern "C" void kernel_launch(void* const* d_in, const int* in_sizes, int n_in,
                              void* d_out, int out_size, void* d_ws, size_t ws_size,
                              hipStream_t stream)
{
    const float* x     = (const float*)d_in[0];
    const int*   ei    = (const int*)d_in[1];
    const float* Wq    = (const float*)d_in[2];
    const float* bq    = (const float*)d_in[3];
    const float* Wk    = (const float*)d_in[4];
    const float* bk    = (const float*)d_in[5];
    const float* Wv    = (const float*)d_in[6];
    const float* bv    = (const float*)d_in[7];
    const float* Wo    = (const float*)d_in[8];
    const float* bo    = (const float*)d_in[9];
    const float* gamma = (const float*)d_in[10];
    const float* beta  = (const float*)d_in[11];
    float* out = (float*)d_out;

    const int N  = in_sizes[0] / 128;
    const int E  = in_sizes[1] / 2;
    const int NB = N * NCHUNK;    // (dst, src-chunk) buckets

    // workspace layout
    char* p = (char*)d_ws;
    unsigned char*  QV8  = (unsigned char*)p;  p += (size_t)N * 256;   // fp8 Q||V
    unsigned char*  K8   = (unsigned char*)p;  p += (size_t)N * 128;   // fp8 K
    unsigned short* aggb = (unsigned short*)p; p += (size_t)N * 128 * 2;
    int* rec_src = (int*)p; p += (size_t)E * 4;
    unsigned short* WqT = (unsigned short*)p; p += 16384 * 2;
    unsigned short* WkT = (unsigned short*)p; p += 16384 * 2;
    unsigned short* WvT = (unsigned short*)p; p += 16384 * 2;
    unsigned short* WoT = (unsigned short*)p; p += 16384 * 2;
    float*    partials = (float*)p;  p += 256 * 4;          // 64 buckets x 4 heads
    unsigned* cnt      = (unsigned*)p; p += (size_t)NB * 4;
    unsigned* off      = (unsigned*)p; p += (size_t)(NB + 1) * 4;
    unsigned* cursor   = (unsigned*)p; p += (size_t)NB * 4;
    unsigned* bsum     = (unsigned*)p; p += 1024 * 4;
    unsigned* bbase    = (unsigned*)p;

    // zero partials + cnt (contiguous)
    (void)hipMemsetAsync(partials, 0, (size_t)(256 + NB) * sizeof(unsigned), stream);

    const int nb  = (N + 127) / 128;
    const int nsc = (NB + 1023) / 1024;
    prep_kernel<<<4, 256, 0, stream>>>(Wq, Wk, Wv, Wo, WqT, WkT, WvT, WoT);
    qkv_mfma<<<nb, 256, 0, stream>>>(x, WqT, WkT, WvT, bq, bk, bv,
                                     QV8, K8, ei, E, cnt, N);
    scan1_kernel<<<nsc, 1024, 0, stream>>>(cnt, off, bsum, NB);
    scan2_kernel<<<1, 1024, 0, stream>>>(bsum, bbase, off, nsc, NB);
    scan3_kernel<<<nsc, 1024, 0, stream>>>(off, cursor, bbase, NB);
    reorder_kernel<<<1024, 256, 0, stream>>>(ei, E, cursor, rec_src);
    node_attn_kernel<<<(N + 3) / 4, 256, 0, stream>>>(QV8, K8, rec_src, off,
                                                      aggb, partials, N);
    out_mfma<<<nb, 256, 0, stream>>>(x, aggb, WoT, bo, gamma, beta, partials,
                                     out, N);
}